// Round 1
// baseline (7647.255 us; speedup 1.0000x reference)
//
#include <hip/hip_runtime.h>
#include <math.h>

#define BQ 256      // batch per encoder
#define B2 512      // combined rows (q ++ r)
#define TT 160
#define EE 256
#define HH 512
#define KK 768      // E + H
#define N4 2048     // 4*H

// ---------------------------------------------------------------------------
// zero h0 and c
__global__ void init_zero(float* __restrict__ h0, float* __restrict__ c) {
    int i = blockIdx.x * blockDim.x + threadIdx.x;   // grid covers B2*HH
    h0[i] = 0.0f;
    c[i]  = 0.0f;
}

// ---------------------------------------------------------------------------
// One LSTM timestep for all 512 rows, GEMM fused with cell update.
// Block = 32 rows x 32 h-units (x 4 gates). 256 threads.
// Thread = 4 rows x 1 h-unit x 4 gates (16 accumulators).
__global__ __launch_bounds__(256) void lstm_step(
    const float* __restrict__ emb,    // [V, E]
    const float* __restrict__ W,      // [768, 2048]  cols: i|j|f|o each 512
    const float* __restrict__ bias,   // [2048]
    const float* __restrict__ wi, const float* __restrict__ wf,
    const float* __restrict__ wo,
    const int* __restrict__ qids, const int* __restrict__ rids,   // [256,160]
    const int* __restrict__ qlen, const int* __restrict__ rlen,   // [256]
    const float* __restrict__ hprev,  // [512, 512]
    float* __restrict__ hnext,        // [512, 512]
    float* __restrict__ c,            // [512, 512] in-place (block-exclusive)
    int t)
{
    __shared__ float sA[16][32];       // [k][row]
    __shared__ float sW[16][32][4];    // [k][h][gate]
    __shared__ int   sId[32];
    __shared__ int   sLen[32];

    const int tid = threadIdx.x;
    const int hb  = blockIdx.x * 32;   // h-unit base
    const int rb  = blockIdx.y * 32;   // row base

    if (tid < 32) {
        int row = rb + tid;
        if (row < BQ) { sId[tid] = qids[row * TT + t];        sLen[tid] = qlen[row]; }
        else          { sId[tid] = rids[(row - BQ) * TT + t]; sLen[tid] = rlen[row - BQ]; }
    }
    __syncthreads();

    const int th  = tid & 31;           // h-unit within tile
    const int tr4 = (tid >> 5) << 2;    // row group base: 0,4,...,28

    // staging assignments
    const int ar = tid >> 3;            // A: row 0..31
    const int ak = (tid & 7) << 1;      // A: k offset 0..14 (even)
    const int wk   = tid >> 4;          // W: k 0..15
    const int wsub = tid & 15;
    const int wg = wsub >> 2;           // W: gate 0..3
    const int wh = (wsub & 3) << 3;     // W: h offset 0,8,16,24

    const int growA = rb + ar;
    const size_t embRow = (size_t)sId[ar] * EE;

    float acc[4][4];                    // [row_i][gate]
    #pragma unroll
    for (int i = 0; i < 4; i++)
        #pragma unroll
        for (int g = 0; g < 4; g++) acc[i][g] = 0.0f;

    for (int kk = 0; kk < KK; kk += 16) {
        // ---- stage A tile (transposed): 16k x 32rows
        {
            int k = kk + ak;            // both k,k+1 on same side of E boundary
            float2 av;
            if (k < EE) av = *reinterpret_cast<const float2*>(&emb[embRow + k]);
            else        av = *reinterpret_cast<const float2*>(&hprev[(size_t)growA * HH + (k - EE)]);
            sA[ak][ar]     = av.x;
            sA[ak + 1][ar] = av.y;
        }
        // ---- stage W tile: [k][h][gate]
        {
            const float* wp = &W[(size_t)(kk + wk) * N4 + wg * HH + hb + wh];
            float4 w0 = *reinterpret_cast<const float4*>(wp);
            float4 w1 = *reinterpret_cast<const float4*>(wp + 4);
            sW[wk][wh + 0][wg] = w0.x; sW[wk][wh + 1][wg] = w0.y;
            sW[wk][wh + 2][wg] = w0.z; sW[wk][wh + 3][wg] = w0.w;
            sW[wk][wh + 4][wg] = w1.x; sW[wk][wh + 5][wg] = w1.y;
            sW[wk][wh + 6][wg] = w1.z; sW[wk][wh + 7][wg] = w1.w;
        }
        __syncthreads();

        #pragma unroll
        for (int k2 = 0; k2 < 16; k2++) {
            float4 a = *reinterpret_cast<const float4*>(&sA[k2][tr4]);   // 4 rows
            float4 w = *reinterpret_cast<const float4*>(&sW[k2][th][0]); // 4 gates
            acc[0][0] += a.x * w.x; acc[0][1] += a.x * w.y; acc[0][2] += a.x * w.z; acc[0][3] += a.x * w.w;
            acc[1][0] += a.y * w.x; acc[1][1] += a.y * w.y; acc[1][2] += a.y * w.z; acc[1][3] += a.y * w.w;
            acc[2][0] += a.z * w.x; acc[2][1] += a.z * w.y; acc[2][2] += a.z * w.z; acc[2][3] += a.z * w.w;
            acc[3][0] += a.w * w.x; acc[3][1] += a.w * w.y; acc[3][2] += a.w * w.z; acc[3][3] += a.w * w.w;
        }
        __syncthreads();
    }

    // ---- fused LSTM cell epilogue (TF gate order i, j, f, o; peepholes)
    const int h = hb + th;
    const float bi = bias[h], bj = bias[HH + h], bfv = bias[2 * HH + h], bo = bias[3 * HH + h];
    const float wih = wi[h], wfh = wf[h], woh = wo[h];
    #pragma unroll
    for (int i = 0; i < 4; i++) {
        const int row = rb + tr4 + i;
        const size_t idx = (size_t)row * HH + h;
        const float zi = acc[i][0] + bi;
        const float zj = acc[i][1] + bj;
        const float zf = acc[i][2] + bfv;
        const float zo = acc[i][3] + bo;
        const float cp = c[idx];
        const float ig = 1.0f / (1.0f + expf(-(zi + wih * cp)));
        const float fg = 1.0f / (1.0f + expf(-(zf + 2.0f + wfh * cp)));
        const float cn = fg * cp + ig * tanhf(zj);
        const float og = 1.0f / (1.0f + expf(-(zo + woh * cn)));
        const float hn = og * tanhf(cn);
        if (t < sLen[tr4 + i]) {
            c[idx] = cn;
            hnext[idx] = hn;
        } else {
            hnext[idx] = hprev[idx];    // freeze state past sequence length
        }
    }
}

// ---------------------------------------------------------------------------
// q_proj[256,512] = h_q[256,512] @ M[512,512]
__global__ __launch_bounds__(512) void proj_kernel(
    const float* __restrict__ h, const float* __restrict__ M,
    float* __restrict__ qp)
{
    const int i = blockIdx.x;
    const int j = threadIdx.x;
    float s = 0.0f;
    for (int k = 0; k < HH; k++) s += h[(size_t)i * HH + k] * M[(size_t)k * HH + j];
    qp[(size_t)i * HH + j] = s;
}

// ---------------------------------------------------------------------------
// C[256,256] = A[256,512] @ B[256,512]^T   (z=0: distances vs r_enc; z=1: echo vs q_enc)
__global__ __launch_bounds__(256) void nt_gemm(
    const float* __restrict__ A,
    const float* __restrict__ B0, const float* __restrict__ B1,
    float* __restrict__ C0, float* __restrict__ C1)
{
    const float* Bm = blockIdx.z ? B1 : B0;
    float* Cm       = blockIdx.z ? C1 : C0;
    __shared__ float sA[16][17];
    __shared__ float sB[16][17];
    const int ti = threadIdx.x >> 4;
    const int tj = threadIdx.x & 15;
    const int ib = blockIdx.y * 16;
    const int jb = blockIdx.x * 16;
    float acc = 0.0f;
    for (int kk = 0; kk < HH; kk += 16) {
        sA[ti][tj] = A [(size_t)(ib + ti) * HH + kk + tj];
        sB[ti][tj] = Bm[(size_t)(jb + ti) * HH + kk + tj];
        __syncthreads();
        #pragma unroll
        for (int k = 0; k < 16; k++) acc += sA[ti][k] * sB[tj][k];
        __syncthreads();
    }
    Cm[(size_t)(ib + ti) * 256 + jb + tj] = acc;
}

__global__ void diag_kernel(const float* __restrict__ dist, float* __restrict__ pos) {
    int i = threadIdx.x;
    pos[i] = dist[(size_t)i * 256 + i];
}

// ---------------------------------------------------------------------------
extern "C" void kernel_launch(void* const* d_in, const int* in_sizes, int n_in,
                              void* d_out, int out_size, void* d_ws, size_t ws_size,
                              hipStream_t stream) {
    const int*   qids = (const int*)d_in[0];
    const int*   rids = (const int*)d_in[1];
    const int*   qlen = (const int*)d_in[2];
    const int*   rlen = (const int*)d_in[3];
    const float* emb  = (const float*)d_in[4];
    const float* W    = (const float*)d_in[5];
    const float* bias = (const float*)d_in[6];
    const float* wi   = (const float*)d_in[7];
    const float* wf   = (const float*)d_in[8];
    const float* wo   = (const float*)d_in[9];
    const float* M    = (const float*)d_in[10];

    float* out       = (float*)d_out;
    float* distances = out;                  // [256,256]
    float* echo      = out + 256 * 256;      // [256,256]
    float* pos       = out + 2 * 256 * 256;  // [256]

    float* h0 = (float*)d_ws;                // [512,512]
    float* h1 = h0 + B2 * HH;                // [512,512]
    float* c  = h1 + B2 * HH;                // [512,512]
    float* qp = c  + B2 * HH;                // [256,512]

    init_zero<<<dim3((B2 * HH) / 256), dim3(256), 0, stream>>>(h0, c);

    float* hp = h0;
    float* hn = h1;
    for (int t = 0; t < TT; t++) {
        lstm_step<<<dim3(16, 16), dim3(256), 0, stream>>>(
            emb, W, bias, wi, wf, wo, qids, rids, qlen, rlen, hp, hn, c, t);
        float* tmp = hp; hp = hn; hn = tmp;
    }
    // hp now holds final h: rows [0,256) = q_enc (== e_enc), rows [256,512) = r_enc

    proj_kernel<<<dim3(256), dim3(512), 0, stream>>>(hp, M, qp);

    nt_gemm<<<dim3(16, 16, 2), dim3(256), 0, stream>>>(
        qp, hp + (size_t)BQ * HH /*r_enc*/, hp /*q_enc*/, distances, echo);

    diag_kernel<<<dim3(1), dim3(256), 0, stream>>>(distances, pos);
}

// Round 3
// 2474.775 us; speedup vs baseline: 3.0901x; 3.0901x over previous
//
#include <hip/hip_runtime.h>
#include <math.h>

#define TT 160
#define EE 256
#define HH 512
#define KK 768
#define B2 512
#define BQ 256

typedef __attribute__((ext_vector_type(8)))  _Float16 half8;
typedef __attribute__((ext_vector_type(16))) float f32x16;

__device__ inline unsigned short f2h(float x) {
    union { _Float16 h; unsigned short u; } v;
    v.h = (_Float16)x;
    return v.u;
}
__device__ inline unsigned int packh2(float a, float b) {
    union { _Float16 h[2]; unsigned int u; } v;
    v.h[0] = (_Float16)a; v.h[1] = (_Float16)b;
    return v.u;
}
__device__ inline float sigmf(float x) { return 1.0f / (1.0f + expf(-x)); }

// ---------------------------------------------------------------------------
// Wt[unit*4+gate][k] = fp16(W[k][gate*512+unit])   (gates interleaved per unit)
__global__ __launch_bounds__(256) void transposeW(const float* __restrict__ W,
                                                  unsigned short* __restrict__ Wt) {
    __shared__ float tile[32][33];
    const int tx = threadIdx.x & 31, ty = threadIdx.x >> 5;
    const int cb = blockIdx.x * 32;   // original col (gate-major)
    const int kb = blockIdx.y * 32;
    #pragma unroll
    for (int j = 0; j < 4; j++)
        tile[ty + j * 8][tx] = W[(size_t)(kb + ty + j * 8) * 2048 + cb + tx];
    __syncthreads();
    #pragma unroll
    for (int j = 0; j < 4; j++) {
        int cl = ty + j * 8;
        int col = cb + cl;
        int gate = col >> 9, unit = col & 511;
        Wt[(size_t)(unit * 4 + gate) * KK + kb + tx] = f2h(tile[tx][cl]);
    }
}

// ---------------------------------------------------------------------------
// One LSTM step: z[512,2048] = fp16([x_t | h]) @ fp16(W), fp32 accum,
// fused peephole cell. Block: 64 rows x 64 cols' (16 units x 4 gates).
// 4 waves, each one 32x32 MFMA tile.
__global__ __launch_bounds__(256) void lstm_step(
    const unsigned short* __restrict__ Wt,   // [2048][768] fp16
    const float* __restrict__ emb,           // [V,256]
    const int* __restrict__ qids, const int* __restrict__ rids,
    const int* __restrict__ qlen, const int* __restrict__ rlen,
    const float* __restrict__ bias,
    const float* __restrict__ wi, const float* __restrict__ wf,
    const float* __restrict__ wo,
    const unsigned short* __restrict__ hbp,  // prev h fp16 [512][512]
    unsigned short* __restrict__ hbn,        // next h fp16
    const float* __restrict__ hfp,           // prev h fp32
    float* __restrict__ hfn,                 // next h fp32
    float* __restrict__ c,                   // [512][512] fp32, in place
    int t)
{
    // LDS: buf0 { A[64][128]fp16 16K, W[64][128]fp16 16K }, buf1 same at +32K.
    // z[64][64] f32 (16K) overlays buf0 A-region after the K loop.
    __shared__ char smem[65536];
    __shared__ int sId[64];
    __shared__ int sLen[64];

    const int tid = threadIdx.x;
    const int bc = blockIdx.x;          // col'-block: units [bc*16, bc*16+16)
    const int rb = blockIdx.y * 64;     // row base

    if (tid < 64) {
        int R = rb + tid;
        sId[tid]  = (R < BQ) ? qids[R * TT + t] : rids[(R - BQ) * TT + t];
        sLen[tid] = (R < BQ) ? qlen[R] : rlen[R - BQ];
    }
    __syncthreads();

    const int l  = tid & 63;
    const int w  = tid >> 6;
    const int wr = w >> 1, wc = w & 1;      // wave tile: rows wr*32, cols wc*32

    // staging map: thread -> (row/col = srow+16s, k-chunk of 8 elems)
    const int srow   = tid >> 4;            // 0..15
    const int schunk = tid & 15;            // 0..15

    f32x16 acc = {0.f,0.f,0.f,0.f,0.f,0.f,0.f,0.f,0.f,0.f,0.f,0.f,0.f,0.f,0.f,0.f};
    int4 aregs[4], wregs[4];

    auto LOADREGS = [&](int tk) {
        const int k0 = tk << 7;
        const int kk = k0 + (schunk << 3);
        #pragma unroll
        for (int s = 0; s < 4; s++) {
            const int row = srow + (s << 4);
            if (k0 < 256) {   // x part: gather fp32 embedding, convert to fp16
                const float* src = emb + (size_t)sId[row] * EE + kk;
                float4 f0 = *(const float4*)src;
                float4 f1 = *(const float4*)(src + 4);
                aregs[s] = make_int4((int)packh2(f0.x, f0.y), (int)packh2(f0.z, f0.w),
                                     (int)packh2(f1.x, f1.y), (int)packh2(f1.z, f1.w));
            } else {          // h part: already fp16
                aregs[s] = *(const int4*)&hbp[(size_t)(rb + row) * HH + (kk - 256)];
            }
            wregs[s] = *(const int4*)&Wt[(size_t)(bc * 64 + row) * KK + kk];
        }
    };
    auto WRITEBUF = [&](int buf) {
        char* base = smem + buf * 32768;
        #pragma unroll
        for (int s = 0; s < 4; s++) {
            const int row = srow + (s << 4);
            const int sw  = ((schunk ^ (row & 15)) << 4);   // XOR-swizzle chunks
            *(int4*)(base + row * 256 + sw)         = aregs[s];
            *(int4*)(base + 16384 + row * 256 + sw) = wregs[s];
        }
    };
    auto COMPUTE = [&](int buf) {
        const char* Ab = smem + buf * 32768;
        const char* Wb = Ab + 16384;
        const int ra = wr * 32 + (l & 31);
        const int cl = wc * 32 + (l & 31);
        const int kg = l >> 5;               // 0/1: which 8-wide k-group
        #pragma unroll
        for (int f = 0; f < 8; f++) {        // 8 k-frags of 16 per 128-K tile
            const int ch = f * 2 + kg;
            half8 av = *(const half8*)(Ab + ra * 256 + ((ch ^ (ra & 15)) << 4));
            half8 wv = *(const half8*)(Wb + cl * 256 + ((ch ^ (cl & 15)) << 4));
            acc = __builtin_amdgcn_mfma_f32_32x32x16_f16(av, wv, acc, 0, 0, 0);
        }
    };

    LOADREGS(0);
    WRITEBUF(0);
    __syncthreads();
    for (int tk = 0; tk < 6; tk++) {
        if (tk < 5) LOADREGS(tk + 1);        // issue next-tile global loads early
        COMPUTE(tk & 1);
        if (tk < 5) { WRITEBUF((tk + 1) & 1); __syncthreads(); }
    }

    // ---- z exchange through LDS (overlay buf0-A region; last compute reads buf1)
    float* zb = (float*)smem;                // [64][64]
    {
        const int colb = wc * 32 + (l & 31);
        const int rowb = wr * 32 + 4 * (l >> 5);
        #pragma unroll
        for (int r = 0; r < 16; r++) {
            const int row = rowb + (r & 3) + 8 * (r >> 2);
            zb[row * 64 + colb] = acc[r];
        }
    }
    __syncthreads();

    // ---- fused peephole LSTM cell (gate order i, j, f, o)
    #pragma unroll
    for (int s = 0; s < 4; s++) {
        const int item = s * 256 + tid;
        const int r = item >> 4;             // 0..63
        const int u = item & 15;             // 0..15
        const int R  = rb + r;
        const int Ug = bc * 16 + u;
        const float4 z4 = *(const float4*)&zb[r * 64 + u * 4];
        const size_t idx = (size_t)R * HH + Ug;
        const float cp = c[idx];
        const float ig = sigmf(z4.x + bias[Ug] + wi[Ug] * cp);
        const float jg = tanhf(z4.y + bias[HH + Ug]);
        const float fg = sigmf(z4.z + bias[2 * HH + Ug] + 2.0f + wf[Ug] * cp);
        const float cn = fg * cp + ig * jg;
        const float og = sigmf(z4.w + bias[3 * HH + Ug] + wo[Ug] * cn);
        const float hn = og * tanhf(cn);
        if (t < sLen[r]) {
            c[idx]   = cn;
            hfn[idx] = hn;
            hbn[idx] = f2h(hn);
        } else {                             // freeze past sequence end
            hfn[idx] = hfp[idx];
            hbn[idx] = hbp[idx];
        }
    }
}

// ---------------------------------------------------------------------------
// q_proj[256,512] = h_q[256,512] @ M[512,512]   (fp32)
__global__ __launch_bounds__(512) void proj_kernel(
    const float* __restrict__ h, const float* __restrict__ M,
    float* __restrict__ qp)
{
    const int i = blockIdx.x;
    const int j = threadIdx.x;
    float s = 0.0f;
    for (int k = 0; k < HH; k++) s += h[(size_t)i * HH + k] * M[(size_t)k * HH + j];
    qp[(size_t)i * HH + j] = s;
}

// C[256,256] = A[256,512] @ B[256,512]^T  (z=0: vs r_enc; z=1: vs q_enc)
__global__ __launch_bounds__(256) void nt_gemm(
    const float* __restrict__ A,
    const float* __restrict__ B0, const float* __restrict__ B1,
    float* __restrict__ C0, float* __restrict__ C1)
{
    const float* Bm = blockIdx.z ? B1 : B0;
    float* Cm       = blockIdx.z ? C1 : C0;
    __shared__ float sA[16][17];
    __shared__ float sB[16][17];
    const int ti = threadIdx.x >> 4;
    const int tj = threadIdx.x & 15;
    const int ib = blockIdx.y * 16;
    const int jb = blockIdx.x * 16;
    float acc = 0.0f;
    for (int kk = 0; kk < HH; kk += 16) {
        sA[ti][tj] = A [(size_t)(ib + ti) * HH + kk + tj];
        sB[ti][tj] = Bm[(size_t)(jb + ti) * HH + kk + tj];
        __syncthreads();
        #pragma unroll
        for (int k = 0; k < 16; k++) acc += sA[ti][k] * sB[tj][k];
        __syncthreads();
    }
    Cm[(size_t)(ib + ti) * 256 + jb + tj] = acc;
}

__global__ void diag_kernel(const float* __restrict__ dist, float* __restrict__ pos) {
    int i = threadIdx.x;
    pos[i] = dist[(size_t)i * 256 + i];
}

// ---------------------------------------------------------------------------
extern "C" void kernel_launch(void* const* d_in, const int* in_sizes, int n_in,
                              void* d_out, int out_size, void* d_ws, size_t ws_size,
                              hipStream_t stream) {
    const int*   qids = (const int*)d_in[0];
    const int*   rids = (const int*)d_in[1];
    const int*   qlen = (const int*)d_in[2];
    const int*   rlen = (const int*)d_in[3];
    const float* emb  = (const float*)d_in[4];
    const float* W    = (const float*)d_in[5];
    const float* bias = (const float*)d_in[6];
    const float* wi   = (const float*)d_in[7];
    const float* wf   = (const float*)d_in[8];
    const float* wo   = (const float*)d_in[9];
    const float* M    = (const float*)d_in[10];

    float* out       = (float*)d_out;
    float* distances = out;
    float* echo      = out + 256 * 256;
    float* pos       = out + 2 * 256 * 256;

    char* ws = (char*)d_ws;
    unsigned short* Wt  = (unsigned short*)(ws);            // 3,145,728 B
    unsigned short* hb0 = (unsigned short*)(ws + 3145728);  //   524,288 B
    unsigned short* hb1 = (unsigned short*)(ws + 3670016);  //   524,288 B
    float* hf0 = (float*)(ws + 4194304);                    // 1,048,576 B
    float* hf1 = (float*)(ws + 5242880);                    // 1,048,576 B
    float* cst = (float*)(ws + 6291456);                    // 1,048,576 B
    float* qp  = (float*)(ws + 7340032);                    //   524,288 B

    // one-time prep (re-run every call; deterministic)
    transposeW<<<dim3(64, 24), dim3(256), 0, stream>>>(W, Wt);
    hipMemsetAsync(hb0, 0, 524288, stream);
    hipMemsetAsync(hf0, 0, 1048576, stream);
    hipMemsetAsync(cst, 0, 1048576, stream);

    const unsigned short* hbp = hb0; unsigned short* hbn = hb1;
    const float* hfp = hf0; float* hfn = hf1;
    for (int t = 0; t < TT; t++) {
        lstm_step<<<dim3(32, 8), dim3(256), 0, stream>>>(
            Wt, emb, qids, rids, qlen, rlen, bias, wi, wf, wo,
            hbp, hbn, hfp, hfn, cst, t);
        const unsigned short* tb = hbp; hbp = hbn; hbn = (unsigned short*)tb;
        const float* tf = hfp; hfp = hfn; hfn = (float*)tf;
    }
    // 160 steps (even) -> final state in hb0/hf0; rows [0,256)=q_enc, [256,512)=r_enc

    proj_kernel<<<dim3(256), dim3(512), 0, stream>>>(hf0, M, qp);
    nt_gemm<<<dim3(16, 16, 2), dim3(256), 0, stream>>>(
        qp, hf0 + (size_t)BQ * HH, hf0, distances, echo);
    diag_kernel<<<dim3(1), dim3(256), 0, stream>>>(distances, pos);
}